// Round 3
// baseline (82.487 us; speedup 1.0000x reference)
//
#include <hip/hip_runtime.h>
#include <float.h>

// RoIPool (torch semantics: round(coords*scale), clamp, AdaptiveMaxPool2d bins)
// features: [B=4, C=128, H=64, W=64] fp32
// rois:     [N=256, 5] fp32  (batch_idx, x1, y1, x2, y2) in image space
// out:      [N, C, 7, 7] fp32
//
// Structure: one thread = one bin x CPT channels. Bin bounds are channel-
// independent, so ROI decode + bin math amortize CPT x, and the CPT*9 pooling
// loads are all independent (single vmcnt window, high ILP).

#define POOL_P 7
#define NBINS  49
#define SPATIAL_SCALE 0.0625f
#define CPT 4                       // channels per thread (C % CPT == 0)

__global__ __launch_bounds__(256) void roipool_kernel(
    const float* __restrict__ feat,
    const float* __restrict__ rois,
    float* __restrict__ out,
    int C, int H, int W, int N)
{
    const int t  = blockIdx.x * blockDim.x + threadIdx.x;
    const int cg = C / CPT;                      // channel groups (32)
    const int total = N * cg * NBINS;
    if (t >= total) return;

    const int bin  = t % NBINS;                  // px-fastest -> coalesced stores
    const int rest = t / NBINS;
    const int c0   = rest % cg;
    const int n    = rest / cg;
    const int px   = bin % POOL_P;
    const int py   = bin / POOL_P;

    // ROI decode (shared by 1568 threads per ROI -> L1 broadcast)
    const float* r = rois + (size_t)n * 5;
    const int b  = (int)r[0];                                  // astype(int32) = trunc
    int x1 = max(__float2int_rn(r[1] * SPATIAL_SCALE), 0);     // jnp.round = half-to-even
    int y1 = max(__float2int_rn(r[2] * SPATIAL_SCALE), 0);
    int x2 = min(__float2int_rn(r[3] * SPATIAL_SCALE), W - 1);
    int y2 = min(__float2int_rn(r[4] * SPATIAL_SCALE), H - 1);

    const int h = y2 - y1 + 1;
    const int w = x2 - x1 + 1;

    // AdaptiveMaxPool2d: start = floor(i*h/P), end = ceil((i+1)*h/P)
    // non-negative operands -> C division == floor; ceil via (a+P-1)/P
    const int ys = y1 + (py * h) / POOL_P;
    const int ye = y1 + ((py + 1) * h + POOL_P - 1) / POOL_P;
    const int xs = x1 + (px * w) / POOL_P;
    const int xe = x1 + ((px + 1) * w + POOL_P - 1) / POOL_P;

    const int ny = ye - ys;                      // 1..3 for this data
    const int nx = xe - xs;

    const size_t HWs     = (size_t)H * W;
    const float* fb      = feat + ((size_t)b * C + c0) * HWs;
    const size_t cstride = (size_t)cg * HWs;     // channel step per k

    float mm[CPT];

    if (ny <= 3 && nx <= 3) {
        // Clamp-instead-of-predicate: OOB taps re-read valid in-bin elements;
        // max over duplicates is identical. No masks needed.
        int off[9];
        #pragma unroll
        for (int dy = 0; dy < 3; ++dy) {
            const int y = ys + min(dy, ny - 1);
            #pragma unroll
            for (int dx = 0; dx < 3; ++dx) {
                const int x = xs + min(dx, nx - 1);
                off[dy * 3 + dx] = y * W + x;
            }
        }
        #pragma unroll
        for (int k = 0; k < CPT; ++k) {
            const float* f = fb + (size_t)k * cstride;
            float m = -FLT_MAX;
            #pragma unroll
            for (int i = 0; i < 9; ++i) m = fmaxf(m, f[off[i]]);
            mm[k] = m;
        }
    } else {
        // Generic fallback: correct for any bin size (no data assumptions).
        #pragma unroll
        for (int k = 0; k < CPT; ++k) {
            const float* f = fb + (size_t)k * cstride;
            float m = -FLT_MAX;                  // empty bin -> finfo(f32).min
            for (int y = ys; y < ye; ++y)
                for (int x = xs; x < xe; ++x)
                    m = fmaxf(m, f[(size_t)y * W + x]);
            mm[k] = m;
        }
    }

    // out[n][c0 + k*cg][py][px]; each k-store is a contiguous coalesced run.
    const size_t obase = ((size_t)n * C + c0) * NBINS + bin;
    #pragma unroll
    for (int k = 0; k < CPT; ++k)
        out[obase + (size_t)k * cg * NBINS] = mm[k];
}

extern "C" void kernel_launch(void* const* d_in, const int* in_sizes, int n_in,
                              void* d_out, int out_size, void* d_ws, size_t ws_size,
                              hipStream_t stream) {
    const float* features = (const float*)d_in[0];   // [B, C, H, W]
    const float* rois     = (const float*)d_in[1];   // [N, 5]
    float* out            = (float*)d_out;           // [N, C, 7, 7]

    const int C = 128, H = 64, W = 64;
    const int N = in_sizes[1] / 5;                   // 256

    const int total = N * (C / CPT) * NBINS;         // 401408
    const int block = 256;
    const int grid  = (total + block - 1) / block;   // 1568

    roipool_kernel<<<grid, block, 0, stream>>>(features, rois, out, C, H, W, N);
}

// Round 4
// 81.534 us; speedup vs baseline: 1.0117x; 1.0117x over previous
//
#include <hip/hip_runtime.h>
#include <float.h>

// RoIPool (torch semantics: round(coords*scale), clamp, AdaptiveMaxPool2d bins)
// features: [B=4, C=128, H=64, W=64] fp32
// rois:     [N=256, 5] fp32  (batch_idx, x1, y1, x2, y2) in image space
// out:      [N, C, 7, 7] fp32
//
// One thread = one bin x CPT channels (decode amortized, 36 independent loads
// in flight). This round: XCD-chunked block swizzle (same-ROI blocks share an
// XCD L2 -> overlapping crop lines hit instead of re-fetching from HBM after
// the harness's 256MiB poison evicts everything) + nontemporal out stores
// (don't evict feature lines from the 4MiB/XCD L2 with write-once data).

#define POOL_P 7
#define NBINS  49
#define SPATIAL_SCALE 0.0625f
#define CPT 4                       // channels per thread (C % CPT == 0)
#define NXCD 8

__global__ __launch_bounds__(256) void roipool_kernel(
    const float* __restrict__ feat,
    const float* __restrict__ rois,
    float* __restrict__ out,
    int C, int H, int W, int N)
{
    // XCD-chunked remap: hardware assigns XCD = blockIdx.x % 8 (round-robin).
    // Bijection valid because grid (1568) % 8 == 0; guarded anyway.
    int bid = blockIdx.x;
    const int nwg = gridDim.x;
    if ((nwg & (NXCD - 1)) == 0)
        bid = (bid & (NXCD - 1)) * (nwg >> 3) + (bid >> 3);

    const int t  = bid * blockDim.x + threadIdx.x;
    const int cg = C / CPT;                      // channel groups (32)
    const int total = N * cg * NBINS;
    if (t >= total) return;

    const int bin  = t % NBINS;                  // px-fastest -> coalesced stores
    const int rest = t / NBINS;
    const int c0   = rest % cg;
    const int n    = rest / cg;
    const int px   = bin % POOL_P;
    const int py   = bin / POOL_P;

    // ROI decode (shared by 1568 threads per ROI -> L1 broadcast)
    const float* r = rois + (size_t)n * 5;
    const int b  = (int)r[0];                                  // astype(int32) = trunc
    int x1 = max(__float2int_rn(r[1] * SPATIAL_SCALE), 0);     // jnp.round = half-to-even
    int y1 = max(__float2int_rn(r[2] * SPATIAL_SCALE), 0);
    int x2 = min(__float2int_rn(r[3] * SPATIAL_SCALE), W - 1);
    int y2 = min(__float2int_rn(r[4] * SPATIAL_SCALE), H - 1);

    const int h = y2 - y1 + 1;
    const int w = x2 - x1 + 1;

    // AdaptiveMaxPool2d: start = floor(i*h/P), end = ceil((i+1)*h/P)
    // non-negative operands -> C division == floor; ceil via (a+P-1)/P
    const int ys = y1 + (py * h) / POOL_P;
    const int ye = y1 + ((py + 1) * h + POOL_P - 1) / POOL_P;
    const int xs = x1 + (px * w) / POOL_P;
    const int xe = x1 + ((px + 1) * w + POOL_P - 1) / POOL_P;

    const int ny = ye - ys;                      // 1..3 for this data
    const int nx = xe - xs;

    const size_t HWs     = (size_t)H * W;
    const float* fb      = feat + ((size_t)b * C + c0) * HWs;
    const size_t cstride = (size_t)cg * HWs;     // channel step per k

    float mm[CPT];

    if (ny <= 3 && nx <= 3) {
        // Clamp-instead-of-predicate: OOB taps re-read valid in-bin elements;
        // max over duplicates is identical. No masks needed.
        int off[9];
        #pragma unroll
        for (int dy = 0; dy < 3; ++dy) {
            const int y = ys + min(dy, ny - 1);
            #pragma unroll
            for (int dx = 0; dx < 3; ++dx) {
                const int x = xs + min(dx, nx - 1);
                off[dy * 3 + dx] = y * W + x;
            }
        }
        #pragma unroll
        for (int k = 0; k < CPT; ++k) {
            const float* f = fb + (size_t)k * cstride;
            float m = -FLT_MAX;
            #pragma unroll
            for (int i = 0; i < 9; ++i) m = fmaxf(m, f[off[i]]);
            mm[k] = m;
        }
    } else {
        // Generic fallback: correct for any bin size (no data assumptions).
        #pragma unroll
        for (int k = 0; k < CPT; ++k) {
            const float* f = fb + (size_t)k * cstride;
            float m = -FLT_MAX;                  // empty bin -> finfo(f32).min
            for (int y = ys; y < ye; ++y)
                for (int x = xs; x < xe; ++x)
                    m = fmaxf(m, f[(size_t)y * W + x]);
            mm[k] = m;
        }
    }

    // out[n][c0 + k*cg][py][px]; write-once data -> nontemporal (skip L2 fill,
    // keep feature lines resident).
    const size_t obase = ((size_t)n * C + c0) * NBINS + bin;
    #pragma unroll
    for (int k = 0; k < CPT; ++k)
        __builtin_nontemporal_store(mm[k], &out[obase + (size_t)k * cg * NBINS]);
}

extern "C" void kernel_launch(void* const* d_in, const int* in_sizes, int n_in,
                              void* d_out, int out_size, void* d_ws, size_t ws_size,
                              hipStream_t stream) {
    const float* features = (const float*)d_in[0];   // [B, C, H, W]
    const float* rois     = (const float*)d_in[1];   // [N, 5]
    float* out            = (float*)d_out;           // [N, C, 7, 7]

    const int C = 128, H = 64, W = 64;
    const int N = in_sizes[1] / 5;                   // 256

    const int total = N * (C / CPT) * NBINS;         // 401408
    const int block = 256;
    const int grid  = (total + block - 1) / block;   // 1568 (divisible by 8)

    roipool_kernel<<<grid, block, 0, stream>>>(features, rois, out, C, H, W, N);
}

// Round 8
// 75.491 us; speedup vs baseline: 1.0927x; 1.0800x over previous
//
#include <hip/hip_runtime.h>
#include <float.h>

// RoIPool (torch semantics: round(coords*scale), clamp, AdaptiveMaxPool2d bins)
// features: [B=4, C=128, H=64, W=64] fp32; rois: [N,5]; out: [N,128,7,7] fp32
//
// Block = (ROI, 16-channel slab): stage crop into LDS (scalar, statically
// in-bounds), pool 49 bins x 16 ch from LDS.
//
// BUGFIX (R4/R6 absmax 3.69): adaptive bins are NOT bounded by ceil(h/P)=3.
// size = ceil((i+1)h/P) - floor(ih/P) <= h/P + 2 -> up to 4 when h=17
// (e.g. i=2: ceil(51/7)-floor(34/7) = 8-4 = 4). The 3x3 unrolled window
// dropped the 4th row/col. Fixed: 4x4 clamped window (dups are max-idempotent),
// guaranteed sufficient for h,w <= 17.

#define POOL_P 7
#define NBINS  49
#define SPATIAL_SCALE 0.0625f
#define SLAB   16                   // channels per block (C/SLAB = 8 slabs)
#define MAXH   17                   // max crop rows in LDS tile (h<=17 proven: delta<256 img px)
#define MAXW   20                   // col span: x1&~3 .. x2 <= 3+16 -> 20 cols
#define TILE   (SLAB * MAXH * MAXW) // 5440 floats = 21760 B

__global__ __launch_bounds__(256) void roipool_kernel(
    const float* __restrict__ feat,
    const float* __restrict__ rois,
    float* __restrict__ out,
    int C, int H, int W, int N)
{
    __shared__ float lds[TILE];

    const int bid  = blockIdx.x;
    const int slab = bid & 7;
    const int n    = bid >> 3;
    const int tid  = threadIdx.x;

    // ROI decode (block-uniform)
    const float* r = rois + (size_t)n * 5;
    const int b  = (int)r[0];                                  // astype(int32) = trunc
    int x1 = max(__float2int_rn(r[1] * SPATIAL_SCALE), 0);     // jnp.round = half-to-even
    int y1 = max(__float2int_rn(r[2] * SPATIAL_SCALE), 0);
    int x2 = min(__float2int_rn(r[3] * SPATIAL_SCALE), W - 1);
    int y2 = min(__float2int_rn(r[4] * SPATIAL_SCALE), H - 1);

    const int h = y2 - y1 + 1;              // 1..17 for this generator
    const int w = x2 - x1 + 1;
    const int xa = x1 & ~3;                 // tile col 0 = xa

    const size_t HWs = (size_t)H * W;
    const float* fb  = feat + ((size_t)b * C + slab * SLAB) * HWs;

    const bool fast = (h <= MAXH) && (w <= MAXW - 3);

    if (fast) {
        // stage: lds[ch*340 + row*20 + col] = feat[ch][y1+min(row,h-1)][min(xa+col,W-1)]
        // clamped rows/cols duplicate valid data; those slots are never read.
        for (int s = tid; s < TILE; s += 256) {
            const int ch  = s / (MAXH * MAXW);
            const int rem = s - ch * (MAXH * MAXW);
            const int row = rem / MAXW;
            const int col = rem - row * MAXW;
            const int y   = y1 + min(row, h - 1);
            const int x   = min(xa + col, W - 1);
            lds[s] = fb[(size_t)ch * HWs + (size_t)y * W + x];
        }
    }
    __syncthreads();

    for (int o = tid; o < NBINS * SLAB; o += 256) {
        const int ch  = o / NBINS;
        const int bin = o - ch * NBINS;
        const int px  = bin % POOL_P;
        const int py  = bin / POOL_P;

        // AdaptiveMaxPool2d: start=floor(i*h/P), end=ceil((i+1)*h/P)
        // non-negative operands -> C division == floor; ceil via (a+P-1)/P
        const int ys = y1 + (py * h) / POOL_P;
        const int ye = y1 + ((py + 1) * h + POOL_P - 1) / POOL_P;
        const int xs = x1 + (px * w) / POOL_P;
        const int xe = x1 + ((px + 1) * w + POOL_P - 1) / POOL_P;
        const int ny = ye - ys;             // 1..4 when h<=17 (<= h/P+2)
        const int nx = xe - xs;

        float m = -FLT_MAX;                 // empty bin -> finfo(f32).min
        if (fast) {
            const int base = ch * (MAXH * MAXW) - y1 * MAXW - xa;
            if (ny <= 4 && nx <= 4) {
                // 4x4 clamped window: duplicate taps are max-idempotent
                #pragma unroll
                for (int dy = 0; dy < 4; ++dy) {
                    const int y = ys + min(dy, ny - 1);
                    #pragma unroll
                    for (int dx = 0; dx < 4; ++dx) {
                        const int x = xs + min(dx, nx - 1);
                        m = fmaxf(m, lds[base + y * MAXW + x]);
                    }
                }
            } else {
                // unreachable for h,w<=17, kept for safety
                for (int y = ys; y < ye; ++y)
                    for (int x = xs; x < xe; ++x)
                        m = fmaxf(m, lds[base + y * MAXW + x]);
            }
        } else {
            // crop too big for LDS tile -> direct global pooling
            const float* f = fb + (size_t)ch * HWs;
            for (int y = ys; y < ye; ++y)
                for (int x = xs; x < xe; ++x)
                    m = fmaxf(m, f[(size_t)y * W + x]);
        }
        out[((size_t)n * C + slab * SLAB + ch) * NBINS + bin] = m;
    }
}

extern "C" void kernel_launch(void* const* d_in, const int* in_sizes, int n_in,
                              void* d_out, int out_size, void* d_ws, size_t ws_size,
                              hipStream_t stream) {
    const float* features = (const float*)d_in[0];   // [B, C, H, W]
    const float* rois     = (const float*)d_in[1];   // [N, 5]
    float* out            = (float*)d_out;           // [N, C, 7, 7]

    const int C = 128, H = 64, W = 64;
    const int N = in_sizes[1] / 5;                   // 256

    const int grid = N * (C / SLAB);                 // 2048
    roipool_kernel<<<grid, 256, 0, stream>>>(features, rois, out, C, H, W, N);
}

// Round 9
// 68.667 us; speedup vs baseline: 1.2013x; 1.0994x over previous
//
#include <hip/hip_runtime.h>
#include <float.h>

// RoIPool (torch semantics: round(coords*scale), clamp, AdaptiveMaxPool2d bins)
// features: [B=4, C=128, H=64, W=64] fp32; rois: [N,5]; out: [N,128,7,7] fp32
//
// Block = (ROI, 16-channel slab): stage crop into LDS, pool 49 bins x 16 ch.
// R8 (scalar staging, fixed 17x20 window) passed at kernel ~28us. This round:
// float4 staging with [row][ch][seg] layout (const-divisor decode, 4x fewer
// instrs) + dynamic h trip count (avg 10.6 of 17 rows -> 1.6x less volume).
// xa = min(x1&~3, W-20) keeps every float4 16B-aligned AND in-row/in-tensor.
//
// Bin window is 4x4: adaptive bin size = ceil((i+1)h/P)-floor(ih/P) <= h/P+2
// <= 4 for h<=17 (R4/R6's absmax-3.69 bug was assuming 3).

#define POOL_P 7
#define NBINS  49
#define SPATIAL_SCALE 0.0625f
#define SLAB   16                   // channels per block (C/SLAB = 8 slabs)
#define MAXH   17                   // max crop rows in LDS tile
#define MAXW   20                   // col span: min(x1&~3, 44) .. +19 covers x1..x2
#define SEGS   (MAXW / 4)           // 5 float4 segments per (row,ch)
#define ROWF4  (SLAB * SEGS)        // 80 float4 per crop row

__global__ __launch_bounds__(256) void roipool_kernel(
    const float* __restrict__ feat,
    const float* __restrict__ rois,
    float* __restrict__ out,
    int C, int H, int W, int N)
{
    __shared__ float4 lds4[MAXH * ROWF4];       // 1360 float4 = 21760 B -> 7 blk/CU
    const float* lds = (const float*)lds4;

    const int bid  = blockIdx.x;
    const int slab = bid & 7;
    const int n    = bid >> 3;
    const int tid  = threadIdx.x;

    // ROI decode (block-uniform)
    const float* r = rois + (size_t)n * 5;
    const int b  = (int)r[0];                                  // astype(int32) = trunc
    int x1 = max(__float2int_rn(r[1] * SPATIAL_SCALE), 0);     // jnp.round = half-to-even
    int y1 = max(__float2int_rn(r[2] * SPATIAL_SCALE), 0);
    int x2 = min(__float2int_rn(r[3] * SPATIAL_SCALE), W - 1);
    int y2 = min(__float2int_rn(r[4] * SPATIAL_SCALE), H - 1);

    const int h = y2 - y1 + 1;                  // 1..17 for this generator
    const int w = x2 - x1 + 1;
    const int xa = min(x1 & ~3, W - MAXW);      // aligned, and xa+19 <= W-1
                                                // pool-read ok: x2 - xa <= 19

    const size_t HWs = (size_t)H * W;
    const float* fb  = feat + ((size_t)b * C + slab * SLAB) * HWs;

    const bool fast = (h <= MAXH) && (w <= MAXW - 3);

    if (fast) {
        // stage h*80 float4 slots: lds4[row*80 + ch*5 + seg] =
        //   feat[ch][y1+row][xa + seg*4 .. +3]   (all aligned, all in-bounds)
        const int hf4 = h * ROWF4;
        for (int s = tid; s < hf4; s += 256) {
            const int row = s / ROWF4;          // const divisors only
            const int rem = s - row * ROWF4;
            const int ch  = rem / SEGS;
            const int seg = rem - ch * SEGS;
            lds4[s] = *(const float4*)(fb + (size_t)ch * HWs
                                          + (size_t)(y1 + row) * W + xa + seg * 4);
        }
    }
    __syncthreads();

    for (int o = tid; o < NBINS * SLAB; o += 256) {
        const int ch  = o / NBINS;
        const int bin = o - ch * NBINS;
        const int px  = bin % POOL_P;
        const int py  = bin / POOL_P;

        // AdaptiveMaxPool2d: start=floor(i*h/P), end=ceil((i+1)*h/P)
        // non-negative operands -> C division == floor; ceil via (a+P-1)/P
        const int ys = y1 + (py * h) / POOL_P;
        const int ye = y1 + ((py + 1) * h + POOL_P - 1) / POOL_P;
        const int xs = x1 + (px * w) / POOL_P;
        const int xe = x1 + ((px + 1) * w + POOL_P - 1) / POOL_P;
        const int ny = ye - ys;                 // 1..4 when h<=17
        const int nx = xe - xs;

        float m = -FLT_MAX;                     // empty bin -> finfo(f32).min
        if (fast) {
            // lds float index: (y-y1)*320 + ch*20 + (x-xa)
            const int base = ch * MAXW - y1 * (ROWF4 * 4) - xa;
            if (ny <= 4 && nx <= 4) {
                // 4x4 clamped window: duplicate taps are max-idempotent
                #pragma unroll
                for (int dy = 0; dy < 4; ++dy) {
                    const int y = ys + min(dy, ny - 1);
                    #pragma unroll
                    for (int dx = 0; dx < 4; ++dx) {
                        const int x = xs + min(dx, nx - 1);
                        m = fmaxf(m, lds[base + y * (ROWF4 * 4) + x]);
                    }
                }
            } else {
                // unreachable for h,w<=17, kept for safety
                for (int y = ys; y < ye; ++y)
                    for (int x = xs; x < xe; ++x)
                        m = fmaxf(m, lds[base + y * (ROWF4 * 4) + x]);
            }
        } else {
            // crop too big for LDS tile -> direct global pooling
            const float* f = fb + (size_t)ch * HWs;
            for (int y = ys; y < ye; ++y)
                for (int x = xs; x < xe; ++x)
                    m = fmaxf(m, f[(size_t)y * W + x]);
        }
        out[((size_t)n * C + slab * SLAB + ch) * NBINS + bin] = m;
    }
}

extern "C" void kernel_launch(void* const* d_in, const int* in_sizes, int n_in,
                              void* d_out, int out_size, void* d_ws, size_t ws_size,
                              hipStream_t stream) {
    const float* features = (const float*)d_in[0];   // [B, C, H, W]
    const float* rois     = (const float*)d_in[1];   // [N, 5]
    float* out            = (float*)d_out;           // [N, C, 7, 7]

    const int C = 128, H = 64, W = 64;
    const int N = in_sizes[1] / 5;                   // 256

    const int grid = N * (C / SLAB);                 // 2048
    roipool_kernel<<<grid, 256, 0, stream>>>(features, rois, out, C, H, W, N);
}

// Round 11
// 67.767 us; speedup vs baseline: 1.2172x; 1.0133x over previous
//
#include <hip/hip_runtime.h>
#include <float.h>

// RoIPool (torch semantics: round(coords*scale), clamp, AdaptiveMaxPool2d bins)
// features: [B=4, C=128, H=64, W=64] fp32; rois: [N,5]; out: [N,128,7,7] fp32
//
// Block = (ROI, 16-channel slab): float4-stage crop into LDS, pool 49x16.
// R10 change: LDS row stride 80 -> 81 float4 (324 floats). R9's 320-float
// stride is 0 mod 32, so bank = (20ch+x)%32 independent of y -> the 7 lanes
// sharing (ch,px) across py in each 4x4 tap hit one bank 7 ways (~2.5x
// serialization). 324 = 4 mod 32 rotates banks with y -> <=2-way (free).
//
// Bin window is 4x4: adaptive bin size = ceil((i+1)h/P)-floor(ih/P) <= h/P+2
// <= 4 for h<=17 (R4/R6's absmax-3.69 bug was assuming 3).

#define POOL_P 7
#define NBINS  49
#define SPATIAL_SCALE 0.0625f
#define SLAB   16                   // channels per block (C/SLAB = 8 slabs)
#define MAXH   17                   // max crop rows in LDS tile
#define MAXW   20                   // col span: min(x1&~3, 44) .. +19 covers x1..x2
#define SEGS   (MAXW / 4)           // 5 float4 segments per (row,ch)
#define ROWF4  (SLAB * SEGS + 1)    // 81 f4 per row (pad breaks 320-stride banks)
#define ROWFL  (ROWF4 * 4)          // 324 floats per row

__global__ __launch_bounds__(256) void roipool_kernel(
    const float* __restrict__ feat,
    const float* __restrict__ rois,
    float* __restrict__ out,
    int C, int H, int W, int N)
{
    __shared__ float4 lds4[MAXH * ROWF4];       // 1377 f4 = 22032 B -> 7 blk/CU
    const float* lds = (const float*)lds4;

    const int bid  = blockIdx.x;
    const int slab = bid & 7;
    const int n    = bid >> 3;
    const int tid  = threadIdx.x;

    // ROI decode (block-uniform)
    const float* r = rois + (size_t)n * 5;
    const int b  = (int)r[0];                                  // astype(int32) = trunc
    int x1 = max(__float2int_rn(r[1] * SPATIAL_SCALE), 0);     // jnp.round = half-to-even
    int y1 = max(__float2int_rn(r[2] * SPATIAL_SCALE), 0);
    int x2 = min(__float2int_rn(r[3] * SPATIAL_SCALE), W - 1);
    int y2 = min(__float2int_rn(r[4] * SPATIAL_SCALE), W - 1 < H - 1 ? W - 1 : H - 1);

    const int h = y2 - y1 + 1;                  // 1..17 for this generator
    const int w = x2 - x1 + 1;
    const int xa = min(x1 & ~3, W - MAXW);      // aligned; xa+19 <= W-1; x2-xa <= 19

    const size_t HWs = (size_t)H * W;
    const float* fb  = feat + ((size_t)b * C + slab * SLAB) * HWs;

    const bool fast = (h <= MAXH) && (w <= MAXW - 3);

    if (fast) {
        // stage h*81 f4 slots (slot 80 of each row skipped):
        // lds4[row*81 + ch*5 + seg] = feat[ch][y1+row][xa+seg*4 ..+3]
        const int hf4 = h * ROWF4;
        for (int s = tid; s < hf4; s += 256) {
            const int row = s / ROWF4;          // const divisors only
            const int rem = s - row * ROWF4;
            if (rem < SLAB * SEGS) {
                const int ch  = rem / SEGS;
                const int seg = rem - ch * SEGS;
                lds4[s] = *(const float4*)(fb + (size_t)ch * HWs
                                              + (size_t)(y1 + row) * W + xa + seg * 4);
            }
        }
    }
    __syncthreads();

    for (int o = tid; o < NBINS * SLAB; o += 256) {
        const int ch  = o / NBINS;
        const int bin = o - ch * NBINS;
        const int px  = bin % POOL_P;
        const int py  = bin / POOL_P;

        // AdaptiveMaxPool2d: start=floor(i*h/P), end=ceil((i+1)*h/P)
        // non-negative operands -> C division == floor; ceil via (a+P-1)/P
        const int ys = y1 + (py * h) / POOL_P;
        const int ye = y1 + ((py + 1) * h + POOL_P - 1) / POOL_P;
        const int xs = x1 + (px * w) / POOL_P;
        const int xe = x1 + ((px + 1) * w + POOL_P - 1) / POOL_P;
        const int ny = ye - ys;                 // 1..4 when h<=17
        const int nx = xe - xs;

        float m = -FLT_MAX;                     // empty bin -> finfo(f32).min
        if (fast) {
            // lds float index: (y-y1)*324 + ch*20 + (x-xa)
            const int base = ch * MAXW - y1 * ROWFL - xa;
            if (ny <= 4 && nx <= 4) {
                // 4x4 clamped window: duplicate taps are max-idempotent
                #pragma unroll
                for (int dy = 0; dy < 4; ++dy) {
                    const int y = ys + min(dy, ny - 1);
                    #pragma unroll
                    for (int dx = 0; dx < 4; ++dx) {
                        const int x = xs + min(dx, nx - 1);
                        m = fmaxf(m, lds[base + y * ROWFL + x]);
                    }
                }
            } else {
                // unreachable for h,w<=17, kept for safety
                for (int y = ys; y < ye; ++y)
                    for (int x = xs; x < xe; ++x)
                        m = fmaxf(m, lds[base + y * ROWFL + x]);
            }
        } else {
            // crop too big for LDS tile -> direct global pooling
            const float* f = fb + (size_t)ch * HWs;
            for (int y = ys; y < ye; ++y)
                for (int x = xs; x < xe; ++x)
                    m = fmaxf(m, f[(size_t)y * W + x]);
        }
        out[((size_t)n * C + slab * SLAB + ch) * NBINS + bin] = m;
    }
}

extern "C" void kernel_launch(void* const* d_in, const int* in_sizes, int n_in,
                              void* d_out, int out_size, void* d_ws, size_t ws_size,
                              hipStream_t stream) {
    const float* features = (const float*)d_in[0];   // [B, C, H, W]
    const float* rois     = (const float*)d_in[1];   // [N, 5]
    float* out            = (float*)d_out;           // [N, C, 7, 7]

    const int C = 128, H = 64, W = 64;
    const int N = in_sizes[1] / 5;                   // 256

    const int grid = N * (C / SLAB);                 // 2048
    roipool_kernel<<<grid, 256, 0, stream>>>(features, rois, out, C, H, W, N);
}